// Round 3
// baseline (550.768 us; speedup 1.0000x reference)
//
#include <hip/hip_runtime.h>

// WassersteinLoss: per-row W1 = (1/N) * sum_i |sort(u)[i] - sort(v)[i]|, mean over rows.
// R3: V=64 — one wave owns a full 4096-row (blocked layout, 64 elems/thread/array).
//   - strides <=32 : in-register CE (57 of 78 passes)
//   - strides 64,128 (m=1,2): DPP quad_perm xor exchange (11 passes, VALU pipe)
//   - strides 256..2048 (m=4..32): ds_bpermute (10 passes, DS pipe)
//   Zero __shared__, zero barriers. R2 post-mortem: DS pipe (4224 bpermute
//   wave-instr/row) was the bottleneck; this cuts wave-DS to 1280/row.

constexpr int N_ELEM  = 4096;
constexpr int V       = 64;     // elements per thread per array
constexpr int THREADS = 256;    // 4 waves = 4 independent rows per block

__device__ __forceinline__ float ce_sel(float a, float o, bool keep_min) {
    return keep_min ? fminf(a, o) : fmaxf(a, o);
}

// ---- compile-time small stages S=2..32 (directions depend on k only) ----
template<int S>
__device__ __forceinline__ void reg_stage_small(float r[V]) {
    #pragma unroll
    for (int s = S >> 1; s >= 1; s >>= 1) {
        #pragma unroll
        for (int k = 0; k < V; ++k) {
            if ((k & s) == 0) {
                const bool asc = ((k & S) == 0);
                float a = r[k], b = r[k + s];
                float lo = fminf(a, b), hi = fmaxf(a, b);
                r[k]     = asc ? lo : hi;
                r[k + s] = asc ? hi : lo;
            }
        }
    }
}

// ---- in-register strides 32..1, runtime (per-lane) direction ----
__device__ __forceinline__ void reg_pass_dyn(float r[V], bool asc) {
    #pragma unroll
    for (int s = 32; s >= 1; s >>= 1) {
        #pragma unroll
        for (int k = 0; k < V; ++k) {
            if ((k & s) == 0) {
                float a = r[k], b = r[k + s];
                float lo = fminf(a, b), hi = fmaxf(a, b);
                r[k]     = asc ? lo : hi;
                r[k + s] = asc ? hi : lo;
            }
        }
    }
}

// ---- lane xor 1 / xor 2 via DPP quad_perm (VALU pipe, no DS) ----
template<int CTRL>
__device__ __forceinline__ void dpp_pass(float ru[V], float rv[V], bool keep_min) {
    #pragma unroll
    for (int k = 0; k < V; ++k) {
        float ou = __int_as_float(__builtin_amdgcn_mov_dpp(
            __float_as_int(ru[k]), CTRL, 0xF, 0xF, true));
        float ov = __int_as_float(__builtin_amdgcn_mov_dpp(
            __float_as_int(rv[k]), CTRL, 0xF, 0xF, true));
        ru[k] = ce_sel(ru[k], ou, keep_min);
        rv[k] = ce_sel(rv[k], ov, keep_min);
    }
}

// ---- lane xor m (m = 4..32) via ds_bpermute ----
__device__ __forceinline__ void bperm_pass(float ru[V], float rv[V],
                                           int pa, bool keep_min) {
    #pragma unroll
    for (int k = 0; k < V; ++k) {
        float ou = __int_as_float(
            __builtin_amdgcn_ds_bpermute(pa, __float_as_int(ru[k])));
        float ov = __int_as_float(
            __builtin_amdgcn_ds_bpermute(pa, __float_as_int(rv[k])));
        ru[k] = ce_sel(ru[k], ou, keep_min);
        rv[k] = ce_sel(rv[k], ov, keep_min);
    }
}

__global__ __launch_bounds__(THREADS) void w1_rows_kernel(
    const float* __restrict__ pred,
    const float* __restrict__ tru,
    float* __restrict__ out,
    float scale)
{
    const int lane = threadIdx.x & 63;
    const int row  = blockIdx.x * (THREADS / 64) + (threadIdx.x >> 6);
    const size_t base = (size_t)row * N_ELEM + (size_t)lane * V;

    // Blocked layout: lane owns global indices [64*lane, 64*lane+64).
    float ru[V], rv[V];
    {
        const float4* u4 = (const float4*)(pred + base);
        const float4* v4 = (const float4*)(tru  + base);
        #pragma unroll
        for (int c = 0; c < V / 4; ++c) {
            float4 a = u4[c], b = v4[c];
            ru[4*c+0] = a.x; ru[4*c+1] = a.y; ru[4*c+2] = a.z; ru[4*c+3] = a.w;
            rv[4*c+0] = b.x; rv[4*c+1] = b.y; rv[4*c+2] = b.z; rv[4*c+3] = b.w;
        }
    }

    // Phase 1: stages S=2..32, fully in-register, compile-time directions.
    reg_stage_small<2>(ru);  reg_stage_small<2>(rv);
    reg_stage_small<4>(ru);  reg_stage_small<4>(rv);
    reg_stage_small<8>(ru);  reg_stage_small<8>(rv);
    reg_stage_small<16>(ru); reg_stage_small<16>(rv);
    reg_stage_small<32>(ru); reg_stage_small<32>(rv);

    // Stage S=64: strides 32..1 in-register, dir from lane bit 0.
    {
        const bool asc = ((lane & 1) == 0);
        reg_pass_dyn(ru, asc);
        reg_pass_dyn(rv, asc);
    }

    // Stages S=128..4096: cross-lane strides (xor m = s>>6), then reg tail.
    for (int S = 128; S <= N_ELEM; S <<= 1) {
        const bool asc = ((lane & (S >> 6)) == 0);   // (g & S)==0, g = lane*64+k
        for (int s = S >> 1; s >= V; s >>= 1) {
            const int  m        = s >> 6;
            const bool keep_min = (((lane & m) == 0) == asc);
            if (m == 1)      dpp_pass<0xB1>(ru, rv, keep_min);          // xor1
            else if (m == 2) dpp_pass<0x4E>(ru, rv, keep_min);          // xor2
            else             bperm_pass(ru, rv, (lane ^ m) << 2, keep_min);
        }
        reg_pass_dyn(ru, asc);
        reg_pass_dyn(rv, asc);
    }

    // Epilogue: sum |sorted_u - sorted_v| (same (lane,k) = same global index).
    float part = 0.f;
    #pragma unroll
    for (int k = 0; k < V; ++k) part += fabsf(ru[k] - rv[k]);

    #pragma unroll
    for (int off = 32; off > 0; off >>= 1)
        part += __shfl_down(part, off, 64);

    if (lane == 0) atomicAdd(out, part * scale);
}

extern "C" void kernel_launch(void* const* d_in, const int* in_sizes, int n_in,
                              void* d_out, int out_size, void* d_ws, size_t ws_size,
                              hipStream_t stream)
{
    (void)n_in; (void)out_size; (void)d_ws; (void)ws_size;

    const float* pred = (const float*)d_in[0];
    const float* tru  = (const float*)d_in[1];
    float* out = (float*)d_out;

    const int B = in_sizes[0] / N_ELEM;   // 4096 rows

    hipMemsetAsync(out, 0, sizeof(float), stream);

    const float scale = 1.0f / ((float)N_ELEM * (float)B);
    w1_rows_kernel<<<B / (THREADS / 64), THREADS, 0, stream>>>(pred, tru, out, scale);
}

// Round 4
// 286.602 us; speedup vs baseline: 1.9217x; 1.9217x over previous
//
#include <hip/hip_runtime.h>

// WassersteinLoss: per-row W1 = (1/N) * sum_i |sort(u)[i] - sort(v)[i]|, mean over rows.
// R4: V=32, 2 waves per row (256-thread block = 2 rows). Blocked layout g = 32t+k.
//   - strides <=16 : in-register CE
//   - lane xor 1,2 : DPP quad_perm (VALU pipe)
//   - lane xor 4..32 : ds_bpermute (DS pipe)
//   - thread xor 64 (one pass, stage 4096) : LDS exchange, stride-33 (2-way alias = free)
//   Sign-negation trick: desc lanes xor sign bit per stage -> ascending-only
//   register tails (2 ops/CE) and direction-independent cross-pass keep side.
// R3 post-mortem: V=64 -> VGPR 180 + tiny grid -> occupancy 11.7%, latency exposed.

constexpr int N_ELEM  = 4096;
constexpr int V       = 32;     // elements per thread per array
constexpr int THREADS = 256;    // 4 waves = 2 rows per block

// ---- compile-time small stages S=2..16 (directions depend on k only) ----
template<int S>
__device__ __forceinline__ void reg_stage_small(float r[V]) {
    #pragma unroll
    for (int s = S >> 1; s >= 1; s >>= 1) {
        #pragma unroll
        for (int k = 0; k < V; ++k) {
            if ((k & s) == 0) {
                const bool asc = ((k & S) == 0);
                float a = r[k], b = r[k + s];
                float lo = fminf(a, b), hi = fmaxf(a, b);
                r[k]     = asc ? lo : hi;
                r[k + s] = asc ? hi : lo;
            }
        }
    }
}

// ---- ascending-only register merge tail, strides 16..1 (2 ops/CE) ----
__device__ __forceinline__ void reg_tail_asc(float r[V]) {
    #pragma unroll
    for (int s = 16; s >= 1; s >>= 1) {
        #pragma unroll
        for (int k = 0; k < V; ++k) {
            if ((k & s) == 0) {
                float a = r[k], b = r[k + s];
                r[k]     = fminf(a, b);
                r[k + s] = fmaxf(a, b);
            }
        }
    }
}

__device__ __forceinline__ void xor_sign(float r[V], unsigned sgn) {
    #pragma unroll
    for (int k = 0; k < V; ++k)
        r[k] = __int_as_float(__float_as_int(r[k]) ^ sgn);
}

__device__ __forceinline__ float ce_sel(float a, float o, bool keep_min) {
    return keep_min ? fminf(a, o) : fmaxf(a, o);
}

// ---- lane xor 1 / xor 2 via DPP quad_perm ----
template<int CTRL>
__device__ __forceinline__ void dpp_pass(float ru[V], float rv[V], bool keep_min) {
    #pragma unroll
    for (int k = 0; k < V; ++k) {
        float ou = __int_as_float(__builtin_amdgcn_mov_dpp(
            __float_as_int(ru[k]), CTRL, 0xF, 0xF, true));
        float ov = __int_as_float(__builtin_amdgcn_mov_dpp(
            __float_as_int(rv[k]), CTRL, 0xF, 0xF, true));
        ru[k] = ce_sel(ru[k], ou, keep_min);
        rv[k] = ce_sel(rv[k], ov, keep_min);
    }
}

// ---- lane xor m (4..32) via ds_bpermute ----
__device__ __forceinline__ void bperm_pass(float ru[V], float rv[V],
                                           int pa, bool keep_min) {
    #pragma unroll
    for (int k = 0; k < V; ++k) {
        float ou = __int_as_float(
            __builtin_amdgcn_ds_bpermute(pa, __float_as_int(ru[k])));
        float ov = __int_as_float(
            __builtin_amdgcn_ds_bpermute(pa, __float_as_int(rv[k])));
        ru[k] = ce_sel(ru[k], ou, keep_min);
        rv[k] = ce_sel(rv[k], ov, keep_min);
    }
}

// ---- cross-lane passes m=MMAX..1 (negated space: keep_min = (lane&m)==0),
//      then ascending register tail. MMAX=0 -> tail only. ----
template<int MMAX>
__device__ __forceinline__ void cross_stage(float ru[V], float rv[V], int lane) {
    #pragma unroll
    for (int m = MMAX; m >= 1; m >>= 1) {
        const bool keep_min = ((lane & m) == 0);
        if (m == 1)      dpp_pass<0xB1>(ru, rv, keep_min);
        else if (m == 2) dpp_pass<0x4E>(ru, rv, keep_min);
        else             bperm_pass(ru, rv, (lane ^ m) << 2, keep_min);
    }
    reg_tail_asc(ru);
    reg_tail_asc(rv);
}

// ---- one full stage S (32..2048): sign-negate desc lanes, cross+tail, restore ----
template<int S, int MMAX>
__device__ __forceinline__ void stage(float ru[V], float rv[V], int t, int lane) {
    const unsigned sgn = ((t & (S >> 5)) == 0) ? 0u : 0x80000000u;
    xor_sign(ru, sgn); xor_sign(rv, sgn);
    cross_stage<MMAX>(ru, rv, lane);
    xor_sign(ru, sgn); xor_sign(rv, sgn);
}

__global__ __launch_bounds__(THREADS, 4) void w1_rows_kernel(
    const float* __restrict__ pred,
    const float* __restrict__ tru,
    float* __restrict__ out,
    float scale)
{
    __shared__ float xbuf[THREADS * 33];   // 33792 B, stride 33 (2-way alias = free)
    __shared__ float wsum[THREADS / 64];

    const int tid  = threadIdx.x;
    const int t    = tid & 127;            // thread index within the row (0..127)
    const int lane = tid & 63;
    const int row  = blockIdx.x * 2 + (tid >> 7);
    const size_t base = (size_t)row * N_ELEM + (size_t)t * V;

    // Blocked layout: row-thread t owns global indices [32t, 32t+32).
    float ru[V], rv[V];
    {
        const float4* u4 = (const float4*)(pred + base);
        const float4* v4 = (const float4*)(tru  + base);
        #pragma unroll
        for (int c = 0; c < V / 4; ++c) {
            float4 a = u4[c], b = v4[c];
            ru[4*c+0] = a.x; ru[4*c+1] = a.y; ru[4*c+2] = a.z; ru[4*c+3] = a.w;
            rv[4*c+0] = b.x; rv[4*c+1] = b.y; rv[4*c+2] = b.z; rv[4*c+3] = b.w;
        }
    }

    // Stages S=2..16: fully in-register, compile-time directions.
    reg_stage_small<2>(ru);  reg_stage_small<2>(rv);
    reg_stage_small<4>(ru);  reg_stage_small<4>(rv);
    reg_stage_small<8>(ru);  reg_stage_small<8>(rv);
    reg_stage_small<16>(ru); reg_stage_small<16>(rv);

    // Stages S=32..2048 (asc bit = t & (S>>5); cross xor m = s>>5).
    stage<32,    0>(ru, rv, t, lane);
    stage<64,    1>(ru, rv, t, lane);
    stage<128,   2>(ru, rv, t, lane);
    stage<256,   4>(ru, rv, t, lane);
    stage<512,   8>(ru, rv, t, lane);
    stage<1024, 16>(ru, rv, t, lane);
    stage<2048, 32>(ru, rv, t, lane);

    // Stage S=4096: ascending everywhere. First pass is thread xor 64 (cross-wave).
    {
        const bool keep_min64 = ((t & 64) == 0);
        const int  wb = tid * 33;
        const int  rb = (tid ^ 64) * 33;

        #pragma unroll
        for (int k = 0; k < V; ++k) xbuf[wb + k] = ru[k];
        __syncthreads();
        #pragma unroll
        for (int k = 0; k < V; ++k)
            ru[k] = ce_sel(ru[k], xbuf[rb + k], keep_min64);
        __syncthreads();

        #pragma unroll
        for (int k = 0; k < V; ++k) xbuf[wb + k] = rv[k];
        __syncthreads();
        #pragma unroll
        for (int k = 0; k < V; ++k)
            rv[k] = ce_sel(rv[k], xbuf[rb + k], keep_min64);
        // no barrier needed before register-only work below

        cross_stage<32>(ru, rv, lane);   // m=32..1 then ascending tail
    }

    // Epilogue: per-thread |diff| sum, wave reduce, block reduce, one atomic.
    float part = 0.f;
    #pragma unroll
    for (int k = 0; k < V; ++k) part += fabsf(ru[k] - rv[k]);

    #pragma unroll
    for (int off = 32; off > 0; off >>= 1)
        part += __shfl_down(part, off, 64);

    const int wid = tid >> 6;
    if (lane == 0) wsum[wid] = part;
    __syncthreads();
    if (tid == 0) {
        float tot = wsum[0] + wsum[1] + wsum[2] + wsum[3];
        atomicAdd(out, tot * scale);
    }
}

extern "C" void kernel_launch(void* const* d_in, const int* in_sizes, int n_in,
                              void* d_out, int out_size, void* d_ws, size_t ws_size,
                              hipStream_t stream)
{
    (void)n_in; (void)out_size; (void)d_ws; (void)ws_size;

    const float* pred = (const float*)d_in[0];
    const float* tru  = (const float*)d_in[1];
    float* out = (float*)d_out;

    const int B = in_sizes[0] / N_ELEM;   // 4096 rows

    hipMemsetAsync(out, 0, sizeof(float), stream);

    const float scale = 1.0f / ((float)N_ELEM * (float)B);
    w1_rows_kernel<<<B / 2, THREADS, 0, stream>>>(pred, tru, out, scale);
}